// Round 6
// baseline (166.986 us; speedup 1.0000x reference)
//
#include <hip/hip_runtime.h>

typedef __attribute__((ext_vector_type(8))) __bf16 bf16x8;
typedef __attribute__((ext_vector_type(4))) __bf16 bf16x4;
typedef __attribute__((ext_vector_type(4))) float f32x4;

#define B_ 16
#define S_ 1024
#define D_ 1024
#define R_ 128

// proj [D][R] fp32  ->  projT [R][D] bf16  (transpose + cast, LDS tiled)
__global__ __launch_bounds__(256) void k_transpose(const float* __restrict__ proj,
                                                   __bf16* __restrict__ projT) {
    __shared__ __bf16 tile[64][66];
    const int k0 = blockIdx.x * 64;
    const int r0 = blockIdx.y * 64;
#pragma unroll
    for (int it = 0; it < 16; ++it) {
        int idx = it * 256 + threadIdx.x;
        int kk = idx >> 6, rr = idx & 63;
        tile[kk][rr] = (__bf16)proj[(size_t)(k0 + kk) * R_ + (r0 + rr)];
    }
    __syncthreads();
#pragma unroll
    for (int it = 0; it < 16; ++it) {
        int idx = it * 256 + threadIdx.x;
        int rr = idx >> 6, kk = idx & 63;
        projT[(size_t)(r0 + rr) * D_ + (k0 + kk)] = tile[kk][rr];
    }
}

// v6: single-pass full-K proj. Block = 16 rows, full N=128, K=1024 in 8
// chunks of 128. Cooperative LDS staging for A (fp32->bf16) and B; MFMA from
// ds_read_b128 (stride 136 elems -> 2-way alias only = free). 1024 blocks,
// 39.4 KB LDS -> 4 blocks/CU, 16 waves/CU. No atomics/memset/finalize.
// Waves n-split: wave w owns cols [w*32, w*32+32).
#define LDA6 136
__global__ __launch_bounds__(256, 4) void k_proj6(const float* __restrict__ batch,
                                                  const __bf16* __restrict__ projT,
                                                  __bf16* __restrict__ t_,
                                                  float* __restrict__ sqn) {
    __shared__ __align__(16) __bf16 smA[16 * LDA6];    // 4.25 KB
    __shared__ __align__(16) __bf16 smB[128 * LDA6];   // 34 KB
    __shared__ float sqpart[4][16];
    const int t = threadIdx.x;
    const int wave = t >> 6, lane = t & 63;
    const int ln = lane & 15, q = lane >> 4;
    const int m0 = blockIdx.x * 16;

    // staging index precompute
    const int arow = t >> 4, aseg = t & 15;   // A: 16 rows x (2 x 16B-dense passes)
    const int brow = t >> 1, bhalf = t & 1;   // B: 128 rows x 2 halves of 64 k

    f32x4 acc[2];
    acc[0] = f32x4{0.f, 0.f, 0.f, 0.f};
    acc[1] = f32x4{0.f, 0.f, 0.f, 0.f};

    for (int c = 0; c < 8; ++c) {
        const int kq = c * 128;
        // ---- stage A: 16 rows x 128 k fp32 -> bf16. Two fully-dense passes:
        // pass p: lanes cover 256 B contiguous per row (16 threads x 16 B).
        {
            const float* src = batch + (size_t)(m0 + arow) * D_ + kq + aseg * 4;
#pragma unroll
            for (int p = 0; p < 2; ++p) {
                float4 v = *(const float4*)(src + p * 64);
                bf16x4 h = {(__bf16)v.x, (__bf16)v.y, (__bf16)v.z, (__bf16)v.w};
                *(bf16x4*)&smA[arow * LDA6 + p * 64 + aseg * 4] = h;
            }
        }
        // ---- stage B: 128 rows x 128 k bf16; thread covers 128 B contiguous.
        {
            const __bf16* src = projT + (size_t)brow * D_ + kq + bhalf * 64;
            __bf16* dst = &smB[brow * LDA6 + bhalf * 64];
#pragma unroll
            for (int i = 0; i < 8; ++i)
                *(bf16x8*)(dst + i * 8) = *(const bf16x8*)(src + i * 8);
        }
        __syncthreads();
#pragma unroll
        for (int k0 = 0; k0 < 4; ++k0) {
            bf16x8 af = *(const bf16x8*)&smA[ln * LDA6 + k0 * 32 + q * 8];
#pragma unroll
            for (int ni = 0; ni < 2; ++ni) {
                bf16x8 bf = *(const bf16x8*)&smB[(wave * 32 + ni * 16 + ln) * LDA6 + k0 * 32 + q * 8];
                acc[ni] = __builtin_amdgcn_mfma_f32_16x16x32_bf16(af, bf, acc[ni], 0, 0, 0);
            }
        }
        __syncthreads();
    }

    // epilogue: D map col = wave*32 + ni*16 + ln, row = m0 + q*4 + r
    float sq[4] = {0.f, 0.f, 0.f, 0.f};
#pragma unroll
    for (int ni = 0; ni < 2; ++ni) {
#pragma unroll
        for (int r = 0; r < 4; ++r) {
            __bf16 h = (__bf16)acc[ni][r];
            t_[(size_t)(m0 + q * 4 + r) * R_ + wave * 32 + ni * 16 + ln] = h;
            float f = (float)h;
            sq[r] += f * f;  // from *rounded* t: diagonal stays consistent
        }
    }
#pragma unroll
    for (int r = 0; r < 4; ++r) {
#pragma unroll
        for (int off = 1; off < 16; off <<= 1)
            sq[r] += __shfl_xor(sq[r], off, 64);
    }
    if (ln == 0) {
#pragma unroll
        for (int r = 0; r < 4; ++r) sqpart[wave][q * 4 + r] = sq[r];
    }
    __syncthreads();
    if (t < 16) {
        float s = sqpart[0][t] + sqpart[1][t] + sqpart[2][t] + sqpart[3][t];
        sqn[m0 + t] = s;
    }
}

// Per batch: cross = t @ t^T; out = max(0, sqn_i + sqn_j - 2*cross).
// LDS-staged tiles, symmetric-transposed float4 stores. (unchanged)
#define GLP 264  // bytes per padded LDS row
__global__ __launch_bounds__(256, 2) void k_gram(const __bf16* __restrict__ t,
                                                 const float* __restrict__ sqn,
                                                 float* __restrict__ out) {
    const int b = blockIdx.z;
    const int wave = threadIdx.x >> 6;
    const int lane = threadIdx.x & 63;
    const int ln = lane & 15;
    const int q  = lane >> 4;
    const int wi = wave >> 1, wj = wave & 1;
    const int i0b = blockIdx.y * 128;
    const int j0b = blockIdx.x * 128;
    const __bf16* tb = t + (size_t)b * S_ * R_;
    const float* sqb = sqn + (size_t)b * S_;

    __shared__ __align__(16) char sm[256 * GLP];
    {
        const __bf16* tis = tb + (size_t)i0b * R_;
        const __bf16* tjs = tb + (size_t)j0b * R_;
#pragma unroll
        for (int it = 0; it < 16; ++it) {
            int u = it * 256 + threadIdx.x;
            int row = u >> 4, ch = u & 15;
            const __bf16* src = (row < 128) ? (tis + (size_t)row * R_)
                                            : (tjs + (size_t)(row - 128) * R_);
            float4 v = *(const float4*)(src + ch * 8);
            *(float4*)(sm + (size_t)row * GLP + ch * 16) = v;
        }
    }
    __syncthreads();

    f32x4 acc[4][4];
#pragma unroll
    for (int mi = 0; mi < 4; ++mi)
#pragma unroll
        for (int ni = 0; ni < 4; ++ni) acc[mi][ni] = f32x4{0.f, 0.f, 0.f, 0.f};

    const char* ibase = sm + (size_t)(wi * 64) * GLP;
    const char* jbase = sm + (size_t)(128 + wj * 64) * GLP;
#pragma unroll
    for (int k0 = 0; k0 < R_; k0 += 32) {
        const int kab = (k0 + q * 8) * 2;
        bf16x8 af[4], bfm[4];
#pragma unroll
        for (int mi = 0; mi < 4; ++mi)
            af[mi] = *(const bf16x8*)(ibase + (size_t)(mi * 16 + ln) * GLP + kab);
#pragma unroll
        for (int ni = 0; ni < 4; ++ni)
            bfm[ni] = *(const bf16x8*)(jbase + (size_t)(ni * 16 + ln) * GLP + kab);
#pragma unroll
        for (int mi = 0; mi < 4; ++mi)
#pragma unroll
            for (int ni = 0; ni < 4; ++ni)
                acc[mi][ni] = __builtin_amdgcn_mfma_f32_16x16x32_bf16(
                    af[mi], bfm[ni], acc[mi][ni], 0, 0, 0);
    }

    const int i0 = i0b + wi * 64;
    const int j0 = j0b + wj * 64;
    float sqj[4];
#pragma unroll
    for (int ni = 0; ni < 4; ++ni) sqj[ni] = sqb[j0 + ni * 16 + ln];

    float* outb = out + (size_t)b * S_ * S_;
#pragma unroll
    for (int mi = 0; mi < 4; ++mi) {
        float4 si4 = *(const float4*)(sqb + i0 + mi * 16 + q * 4);
#pragma unroll
        for (int ni = 0; ni < 4; ++ni) {
            const int j = j0 + ni * 16 + ln;
            float4 o;
            o.x = fmaxf(si4.x + sqj[ni] - 2.f * acc[mi][ni][0], 0.f);
            o.y = fmaxf(si4.y + sqj[ni] - 2.f * acc[mi][ni][1], 0.f);
            o.z = fmaxf(si4.z + sqj[ni] - 2.f * acc[mi][ni][2], 0.f);
            o.w = fmaxf(si4.w + sqj[ni] - 2.f * acc[mi][ni][3], 0.f);
            *(float4*)(outb + (size_t)j * S_ + i0 + mi * 16 + q * 4) = o;
        }
    }
}

extern "C" void kernel_launch(void* const* d_in, const int* in_sizes, int n_in,
                              void* d_out, int out_size, void* d_ws, size_t ws_size,
                              hipStream_t stream) {
    const float* batch = (const float*)d_in[0];  // [16,1024,1024] fp32
    const float* proj  = (const float*)d_in[1];  // [1024,128] fp32
    float* out = (float*)d_out;                  // [16,1024,1024] fp32

    char* ws = (char*)d_ws;
    const size_t T_B     = (size_t)B_ * S_ * R_ * 2;   // 4 MB
    const size_t PROJT_B = (size_t)R_ * D_ * 2;        // 256 KB

    __bf16* t     = (__bf16*)ws;
    __bf16* projT = (__bf16*)(ws + T_B);
    float*  sqn   = (float*)(ws + T_B + PROJT_B);

    k_transpose<<<dim3(D_ / 64, R_ / 64), 256, 0, stream>>>(proj, projT);
    k_proj6<<<dim3((B_ * S_) / 16), 256, 0, stream>>>(batch, projT, t, sqn);
    k_gram<<<dim3(S_ / 128, S_ / 128, B_), 256, 0, stream>>>(t, sqn, out);
}